// Round 3
// baseline (91153.754 us; speedup 1.0000x reference)
//
#include <hip/hip_runtime.h>
#include <stdint.h>

// ============================================================================
// ScannedMultiLayerLSTM: T=64, B=32, W=1024, L=4
// Round 6: XCD-local recurrence + feeder split.
//   Insight: per-step period = recurrent-h handoff latency. R3/R4/R5 all hit
//   ~14us/cell because layer blocks scatter over all 8 XCDs -> every h
//   exchange pays the MALL round trip. Fix: only Wh (8.4MB/layer) must be
//   register-resident on the critical path, and it fits one XCD (32 CUs).
//   - recurrent blocks: XCD l (bid%8==l<4), 32 blocks/layer, Wh only (K=1024)
//     h exchanged via plain stores -> own-XCD L2, sc0 sentinel polls
//   - feeder blocks: XCD 4+l, hold Wx, compute xgate=y*Wx+b pipelined,
//     publish via MALL (sc0 sc1). Only a constant offset, not per-step.
//   - XCC_ID table + per-chunk local/global choice; bounded timeout flips
//     stale local chunks to the global path (deadlock-free, mapping-agnostic)
//   - dual publish h: plain (local) + sc0 sc1 (global: feeders + fallback)
// ============================================================================

typedef unsigned short u16;
typedef unsigned int u32;
typedef unsigned long long u64;
typedef __attribute__((ext_vector_type(8))) short short8;
typedef __attribute__((ext_vector_type(4))) float f32x4;
typedef __attribute__((ext_vector_type(4))) unsigned int u32x4;
typedef __attribute__((ext_vector_type(2))) unsigned int u32x2;

#define NT 64
#define NB 32
#define NW 1024
#define NLAY 4
#define G4 4096
#define BW 32768  // NB*NW u16 per hist slot
#define POISON 0xAAAAAAAAu
#define POISON16 0xAAAAu

// workspace layout (bytes)
#define GH_OFF 0                  // bf16 gh[L][65][B][W]  (global/MALL h)
#define LH_OFF 17039360           // bf16 lh[L][65][B][W]  (XCD-local h)
#define XG_OFF 34078720           // xgate[L][64][B][4W]  f32 or bf16

__device__ __forceinline__ float bf2f(u16 u) {
  union { u32 i; float f; } v; v.i = ((u32)u) << 16; return v.f;
}
__device__ __forceinline__ u16 f2bf(float f) {
  union { float f; u32 i; } v; v.f = f;
  u32 b = v.i;
  return (u16)((b + 0x7FFFu + ((b >> 16) & 1u)) >> 16);
}
__device__ __forceinline__ float sigmoidf_(float x) { return 1.f / (1.f + __expf(-x)); }
__device__ __forceinline__ float tanhfast(float x) {
  float cx = fminf(fmaxf(x, -15.f), 15.f);
  float e = __expf(2.f * cx);
  return (e - 1.f) / (e + 1.f);
}
union CastU { u32x4 u; short8 s; };
__device__ __forceinline__ short8 as_s8(u32x4 v) { CastU c; c.u = v; return c.s; }
__device__ __forceinline__ u32x4 as_u4(short8 v) { CastU c; c.s = v; return c.u; }
__device__ __forceinline__ bool fresh4(u32x4 v) {
  return (v.x != POISON) && (v.y != POISON) && (v.z != POISON) && (v.w != POISON);
}

#define WAITCNT_ALL(r)                                                                        \
  asm volatile("s_waitcnt vmcnt(0)"                                                           \
               : "+v"(r[0]), "+v"(r[1]), "+v"(r[2]), "+v"(r[3]), "+v"(r[4]), "+v"(r[5]),      \
                 "+v"(r[6]), "+v"(r[7]), "+v"(r[8]), "+v"(r[9]), "+v"(r[10]), "+v"(r[11]),    \
                 "+v"(r[12]), "+v"(r[13]), "+v"(r[14]), "+v"(r[15])                           \
               :                                                                              \
               : "memory")

// ---------------------------------------------------------------------------
// mixed-path sentinel poll: 16 chunks (2 rows x 8). Chunk q uses the LOCAL
// (sc0, own-L2) path if bit q of lmask is set, else GLOBAL (sc0 sc1, MALL).
// Incremental stale re-poll; after ~2000 rounds still-stale local chunks are
// flipped to global (breaks deadlock if the XCD mapping assumption fails).
// ---------------------------------------------------------------------------
__device__ __forceinline__ void poll_mixed(const u16* lA, const u16* gA,
                                           const u16* lB, const u16* gB,
                                           u32& lmask, u32x4 r[16]) {
#pragma unroll
  for (int q = 0; q < 8; ++q) {
    if ((lmask >> q) & 1u) {
      asm volatile("global_load_dwordx4 %0, %1, off sc0" : "=v"(r[q]) : "v"(lA + q * 32));
      asm volatile("global_load_dwordx4 %0, %1, off sc0" : "=v"(r[8 + q]) : "v"(lB + q * 32));
    } else {
      asm volatile("global_load_dwordx4 %0, %1, off sc0 sc1" : "=v"(r[q]) : "v"(gA + q * 32));
      asm volatile("global_load_dwordx4 %0, %1, off sc0 sc1" : "=v"(r[8 + q]) : "v"(gB + q * 32));
    }
  }
  WAITCNT_ALL(r);
  u32 stale = 0;
#pragma unroll
  for (int c = 0; c < 16; ++c)
    if (!fresh4(r[c])) stale |= (1u << c);
  int rounds = 0;
  while (__any(stale != 0)) {
    if (++rounds > 2000) {  // mapping broken for these chunks -> go global
      u32 flip = ((stale | (stale >> 8)) & 0xFFu) & lmask;
      lmask &= ~flip;
      rounds = 0;
    }
    if (__all(stale == 0xFFFFu)) __builtin_amdgcn_s_sleep(1);
#pragma unroll
    for (int c = 0; c < 16; ++c) {
      if (stale & (1u << c)) {
        int q = c & 7;
        bool loc = (lmask >> q) & 1u;
        const u16* p = (c < 8) ? ((loc ? lA : gA) + q * 32) : ((loc ? lB : gB) + q * 32);
        if (loc)
          asm volatile("global_load_dwordx4 %0, %1, off sc0" : "=v"(r[c]) : "v"(p));
        else
          asm volatile("global_load_dwordx4 %0, %1, off sc0 sc1" : "=v"(r[c]) : "v"(p));
      }
    }
    WAITCNT_ALL(r);
#pragma unroll
    for (int c = 0; c < 16; ++c)
      if ((stale & (1u << c)) && fresh4(r[c])) stale &= ~(1u << c);
  }
}

// ---------------------------------------------------------------------------
// setup: dtype detect, reset normalize, xcd-table init. 1 block x 256.
// ---------------------------------------------------------------------------
__global__ void lstm_setup(const void* __restrict__ x, const void* __restrict__ resets,
                           int* __restrict__ modes, int* __restrict__ rmask,
                           u32* __restrict__ tbl) {
  __shared__ int votes_bf16, bad_int, bad_float;
  __shared__ int sm_rmode;
  int tid = threadIdx.x;
  if (tid == 0) { votes_bf16 = 0; bad_int = 0; bad_float = 0; }
  __syncthreads();
  {
    u32 w = ((const u32*)x)[tid];
    int e = (int)((w >> 7) & 0xFFu);
    if (e >= 100 && e <= 140) atomicAdd(&votes_bf16, 1);
  }
  if (tid < 128) {
    u32 r = ((const u32*)resets)[tid];
    if (r > 1u) atomicAdd(&bad_int, 1);
    if (r != 0u && r != 0x3F800000u) atomicAdd(&bad_float, 1);
  }
  __syncthreads();
  if (tid == 0) {
    int mbf = (votes_bf16 >= 192) ? 1 : 0;
    int rmode;
    if (bad_int == 0) rmode = 1;
    else if (bad_float == 0) rmode = 2;
    else rmode = 0;
    modes[0] = mbf;
    modes[1] = rmode;
    sm_rmode = rmode;
  }
  __syncthreads();
  int rmode = sm_rmode;
#pragma unroll
  for (int k = 0; k < 8; ++k) {
    int idx = tid * 8 + k;
    int val;
    if (rmode == 1) val = (((const int*)resets)[idx] != 0);
    else if (rmode == 2) val = (((const u32*)resets)[idx] != 0u);
    else val = (((const unsigned char*)resets)[idx] != 0);
    rmask[idx] = val;
  }
  if (tid < 128) tbl[tid] = 0xFFFFFFFFu;
}

// ---------------------------------------------------------------------------
// poison [ws, ws + n4*16) with sentinel. grid-stride.
// ---------------------------------------------------------------------------
__global__ void lstm_poison(u32* __restrict__ p, long n4) {
  long i = (long)blockIdx.x * 256 + threadIdx.x;
  long stride = (long)gridDim.x * 256;
  u32x4 v = {POISON, POISON, POISON, POISON};
  for (; i < n4; i += stride) *(u32x4*)(p + i * 4) = v;
}

// ---------------------------------------------------------------------------
// prep: h0 -> gh slot0 AND lh slot0. 512 blocks x 256.
// ---------------------------------------------------------------------------
template <bool BF16>
__global__ void lstm_prep(const void* __restrict__ h0, const int* __restrict__ modes,
                          u16* __restrict__ gh, u16* __restrict__ lh) {
  if ((modes[0] != 0) != BF16) return;
  int idx = blockIdx.x * 256 + threadIdx.x;  // [L][B][W]
  int l = idx >> 15;
  int rem = idx & 32767;
  float hv = BF16 ? bf2f(((const u16*)h0)[idx]) : ((const float*)h0)[idx];
  u16 b = f2bf(hv);
  gh[(size_t)l * 65 * BW + rem] = b;
  lh[(size_t)l * 65 * BW + rem] = b;
}

// ---------------------------------------------------------------------------
// main persistent kernel. 256 blocks x 256 threads (4 waves).
// bid%8 < 4: recurrent (layer=bid%8, Wh);  >=4: feeder (layer=bid%8-4, Wx).
// Per block: 32 hidden units (ub..ub+31), 128 gate cols.
// Waves: w0={i,f | k 0-511}, w1={i,f | k 512-1023}, w2={g,o | lo}, w3={g,o | hi}
// ---------------------------------------------------------------------------
template <bool BF16>
__global__ __launch_bounds__(256, 1) void lstm_main(
    const void* __restrict__ xv, const void* __restrict__ Wxv,
    const void* __restrict__ Whv, const void* __restrict__ biasv,
    const void* __restrict__ c0v, void* __restrict__ outv,
    const int* __restrict__ modes, const int* __restrict__ rmask,
    u16* __restrict__ gh, u16* __restrict__ lh, void* __restrict__ xg,
    u32* __restrict__ tbl, int xg32) {
  if ((modes[0] != 0) != BF16) return;

  const int bid = blockIdx.x;
  const int xcd8 = bid & 7;
  const int grp = bid >> 3;           // 0..31
  const bool rec = (xcd8 < 4);
  const int l = rec ? xcd8 : (xcd8 - 4);
  const int ub = grp * 32;            // unit base
  const int tid = threadIdx.x;
  const int wave = tid >> 6;
  const int lane = tid & 63;
  const int lrow = lane & 15;
  const int lk8 = (lane >> 4) * 8;
  const int gpair = (wave >> 1) & 1;  // 0: gates i,f  1: gates g,o
  const int khalf = wave & 1;         // k offset 0 / 512

  __shared__ float red[2][2][4][16][17];  // [gpair][mt][nt][row][col+pad]

  // ---- weight preload: B-frags for 4 ntiles x 16 ktiles ----
  short8 wfrag[4][16];
  {
    const size_t base = (size_t)l * NW * G4;
#pragma unroll
    for (int nt = 0; nt < 4; ++nt) {
      const int col = (gpair * 2 + (nt >> 1)) * 1024 + ub + (nt & 1) * 16 + lrow;
#pragma unroll
      for (int kt = 0; kt < 16; ++kt) {
        size_t off = base + (size_t)(khalf * 512 + kt * 32 + lk8) * G4 + (size_t)col;
        short8 v;
        if (BF16) {
          const u16* p = (rec ? (const u16*)Whv : (const u16*)Wxv) + off;
#pragma unroll
          for (int j = 0; j < 8; ++j) v[j] = (short)p[(size_t)j * G4];
        } else {
          const float* p = (rec ? (const float*)Whv : (const float*)Wxv) + off;
#pragma unroll
          for (int j = 0; j < 8; ++j) v[j] = (short)f2bf(p[(size_t)j * G4]);
        }
        wfrag[nt][kt] = v;
      }
    }
  }

  if (rec) {
    // ---- publish + read XCD map; build per-source-slice locality mask ----
    u32 myxcd;
    asm volatile("s_getreg_b32 %0, hwreg(HW_REG_XCC_ID)" : "=s"(myxcd));
    myxcd &= 0xFu;
    if (tid == 0) {
      u32* tp = tbl + l * 32 + grp;
      asm volatile("global_store_dword %0, %1, off sc0 sc1" : : "v"(tp), "v"(myxcd) : "memory");
    }
    u32 slicemask;
    {
      const u32* tp = tbl + l * 32 + (lane & 31);
      u32 e;
      for (;;) {
        asm volatile("global_load_dword %0, %1, off sc0 sc1" : "=v"(e) : "v"(tp));
        asm volatile("s_waitcnt vmcnt(0)" : "+v"(e) : : "memory");
        if (__all(e != 0xFFFFFFFFu)) break;
        __builtin_amdgcn_s_sleep(1);
      }
      u64 bal = __ballot(e == myxcd);
      slicemask = (u32)(bal & 0xFFFFFFFFull) & (u32)(bal >> 32);
    }
    u32 lmask[2];
    lmask[0] = (slicemask >> (khalf * 16)) & 0xFFu;
    lmask[1] = (slicemask >> (khalf * 16 + 8)) & 0xFFu;

    const int eb = tid >> 3;        // epilogue batch row
    const int eu = (tid & 7) * 4;   // epilogue unit base (4 cells/thread)
    float creg[4] = {0.f, 0.f, 0.f, 0.f};

#pragma unroll 1
    for (int t = 0; t < NT; ++t) {
      // ---- xgate prefetch (validated in epilogue) ----
      u32x4 xr[4];
      u32x2 xr2[4];
      const float* xbf = (const float*)xg + ((size_t)(l * 64 + t) * NB + eb) * G4 + ub + eu;
      const u16* xbh = (const u16*)xg + ((size_t)(l * 64 + t) * NB + eb) * G4 + ub + eu;
      if (xg32) {
#pragma unroll
        for (int g = 0; g < 4; ++g)
          asm volatile("global_load_dwordx4 %0, %1, off sc0 sc1" : "=v"(xr[g]) : "v"(xbf + g * 1024));
      } else {
#pragma unroll
        for (int g = 0; g < 4; ++g)
          asm volatile("global_load_dwordx2 %0, %1, off sc0 sc1" : "=v"(xr2[g]) : "v"(xbh + g * 1024));
      }

      const u16* sL = lh + (size_t)(l * 65 + t) * BW;
      const u16* sG = gh + (size_t)(l * 65 + t) * BW;
      int rm0 = rmask[t * NB + lrow];
      int rm1 = rmask[t * NB + 16 + lrow];

      f32x4 acc[2][4];
      f32x4 zf = {0.f, 0.f, 0.f, 0.f};
#pragma unroll
      for (int mt = 0; mt < 2; ++mt)
#pragma unroll
        for (int nt = 0; nt < 4; ++nt) acc[mt][nt] = zf;

#pragma unroll
      for (int h2 = 0; h2 < 2; ++h2) {
        u32x4 r[16];
        const int kb = khalf * 512 + h2 * 256 + lk8;
        poll_mixed(sL + (size_t)lrow * NW + kb, sG + (size_t)lrow * NW + kb,
                   sL + (size_t)(lrow + 16) * NW + kb, sG + (size_t)(lrow + 16) * NW + kb,
                   lmask[h2], r);
        u32x4 z4 = {0u, 0u, 0u, 0u};
        if (rm0) {
#pragma unroll
          for (int q = 0; q < 8; ++q) r[q] = z4;
        }
        if (rm1) {
#pragma unroll
          for (int q = 0; q < 8; ++q) r[8 + q] = z4;
        }
#pragma unroll
        for (int q = 0; q < 8; ++q) {
          const int kt = h2 * 8 + q;
#pragma unroll
          for (int nt = 0; nt < 4; ++nt) {
            acc[0][nt] = __builtin_amdgcn_mfma_f32_16x16x32_bf16(as_s8(r[q]), wfrag[nt][kt], acc[0][nt], 0, 0, 0);
            acc[1][nt] = __builtin_amdgcn_mfma_f32_16x16x32_bf16(as_s8(r[8 + q]), wfrag[nt][kt], acc[1][nt], 0, 0, 0);
          }
        }
      }

      // ---- 3-phase cross-wave K reduce (w1->w0, w3->w2) ----
      if (khalf == 1) {
#pragma unroll
        for (int mt = 0; mt < 2; ++mt)
#pragma unroll
          for (int nt = 0; nt < 4; ++nt)
#pragma unroll
            for (int e = 0; e < 4; ++e)
              red[gpair][mt][nt][(lane >> 4) * 4 + e][lrow] = acc[mt][nt][e];
      }
      __syncthreads();
      if (khalf == 0) {
#pragma unroll
        for (int mt = 0; mt < 2; ++mt)
#pragma unroll
          for (int nt = 0; nt < 4; ++nt)
#pragma unroll
            for (int e = 0; e < 4; ++e)
              acc[mt][nt][e] += red[gpair][mt][nt][(lane >> 4) * 4 + e][lrow];
      }
      __syncthreads();
      if (khalf == 0) {
#pragma unroll
        for (int mt = 0; mt < 2; ++mt)
#pragma unroll
          for (int nt = 0; nt < 4; ++nt)
#pragma unroll
            for (int e = 0; e < 4; ++e)
              red[gpair][mt][nt][(lane >> 4) * 4 + e][lrow] = acc[mt][nt][e];
      }
      __syncthreads();

      // ---- epilogue: validate xgate, 4 cells per thread ----
      {
        if (xg32) {
          for (;;) {
            asm volatile("s_waitcnt vmcnt(0)"
                         : "+v"(xr[0]), "+v"(xr[1]), "+v"(xr[2]), "+v"(xr[3]) : : "memory");
            bool ok = true;
#pragma unroll
            for (int g = 0; g < 4; ++g) ok &= fresh4(xr[g]);
            if (__all(ok)) break;
            if (!ok) {
#pragma unroll
              for (int g = 0; g < 4; ++g)
                asm volatile("global_load_dwordx4 %0, %1, off sc0 sc1" : "=v"(xr[g]) : "v"(xbf + g * 1024));
            }
          }
        } else {
          for (;;) {
            asm volatile("s_waitcnt vmcnt(0)"
                         : "+v"(xr2[0]), "+v"(xr2[1]), "+v"(xr2[2]), "+v"(xr2[3]) : : "memory");
            bool ok = true;
#pragma unroll
            for (int g = 0; g < 4; ++g) {
              u32 w0 = xr2[g].x, w1 = xr2[g].y;
              ok &= ((w0 & 0xFFFFu) != POISON16) && ((w0 >> 16) != POISON16) &&
                    ((w1 & 0xFFFFu) != POISON16) && ((w1 >> 16) != POISON16);
            }
            if (__all(ok)) break;
            if (!ok) {
#pragma unroll
              for (int g = 0; g < 4; ++g)
                asm volatile("global_load_dwordx2 %0, %1, off sc0 sc1" : "=v"(xr2[g]) : "v"(xbh + g * 1024));
            }
          }
        }

        int rm = rmask[t * NB + eb];
        float hn[4];
#pragma unroll
        for (int j = 0; j < 4; ++j) {
          const int u = eu + j;
          float gv[4];
#pragma unroll
          for (int g = 0; g < 4; ++g) {
            float xga;
            if (xg32) {
              union { u32 u; float f; } cv;
              cv.u = xr[g][j];
              xga = cv.f;
            } else {
              u32 w = xr2[g][j >> 1];
              xga = bf2f((u16)((w >> ((j & 1) * 16)) & 0xFFFFu));
            }
            gv[g] = red[g >> 1][eb >> 4][(g & 1) * 2 + (u >> 4)][eb & 15][u & 15] + xga;
          }
          float c_old = creg[j];
          if (t == 0) {
            int cidx = (l * NB + eb) * NW + ub + u;
            c_old = BF16 ? bf2f(((const u16*)c0v)[cidx]) : ((const float*)c0v)[cidx];
          }
          if (rm) c_old = 0.f;
          float ci = sigmoidf_(gv[0]);
          float cf = sigmoidf_(gv[1]);
          float cg = tanhfast(gv[2]);
          float co = sigmoidf_(gv[3]);
          float cn = cf * c_old + ci * cg;
          hn[j] = co * tanhfast(cn);
          creg[j] = cn;
        }
        // dual publish h: local (plain -> own L2) + global (sc0 sc1 -> MALL)
        u32x2 hp;
        hp.x = (u32)f2bf(hn[0]) | ((u32)f2bf(hn[1]) << 16);
        hp.y = (u32)f2bf(hn[2]) | ((u32)f2bf(hn[3]) << 16);
        size_t hoff = (size_t)(l * 65 + t + 1) * BW + (size_t)eb * NW + ub + eu;
        u16* lp = lh + hoff;
        u16* gp = gh + hoff;
        asm volatile("global_store_dwordx2 %0, %1, off" : : "v"(lp), "v"(hp) : "memory");
        asm volatile("global_store_dwordx2 %0, %1, off sc0 sc1" : : "v"(gp), "v"(hp) : "memory");
        if (l == NLAY - 1) {
          size_t oy = ((size_t)t * NB + eb) * NW + ub + eu;
          if (BF16) *(u32x2*)((u32*)outv + (oy >> 1)) = hp;
          else {
            float* op = (float*)outv + oy;
            op[0] = hn[0]; op[1] = hn[1]; op[2] = hn[2]; op[3] = hn[3];
          }
        }
        if (t == NT - 1) {
          size_t oc = (size_t)NT * NB * NW + ((size_t)l * NB + eb) * NW + ub + eu;
          size_t oh = oc + (size_t)NLAY * NB * NW;
          if (BF16) {
            u32x2 cp;
            cp.x = (u32)f2bf(creg[0]) | ((u32)f2bf(creg[1]) << 16);
            cp.y = (u32)f2bf(creg[2]) | ((u32)f2bf(creg[3]) << 16);
            *(u32x2*)((u32*)outv + (oc >> 1)) = cp;
            *(u32x2*)((u32*)outv + (oh >> 1)) = hp;
          } else {
            float* ov = (float*)outv;
            ov[oc + 0] = creg[0]; ov[oc + 1] = creg[1]; ov[oc + 2] = creg[2]; ov[oc + 3] = creg[3];
            ov[oh + 0] = hn[0]; ov[oh + 1] = hn[1]; ov[oh + 2] = hn[2]; ov[oh + 3] = hn[3];
          }
        }
      }
      __syncthreads();  // protect red[] for next step
    }
  } else {
    // ======================= FEEDER: xgate = y*Wx + b =======================
    float bias_r[4];
#pragma unroll
    for (int nt = 0; nt < 4; ++nt) {
      int col = (gpair * 2 + (nt >> 1)) * 1024 + ub + (nt & 1) * 16 + lrow;
      int bidx = l * G4 + col;
      bias_r[nt] = BF16 ? bf2f(((const u16*)biasv)[bidx]) : ((const float*)biasv)[bidx];
    }
    u32 zmask = 0;  // always global

#pragma unroll 1
    for (int t = 0; t < NT; ++t) {
      f32x4 acc[2][4];
      f32x4 zf = {0.f, 0.f, 0.f, 0.f};
#pragma unroll
      for (int mt = 0; mt < 2; ++mt)
#pragma unroll
        for (int nt = 0; nt < 4; ++nt) acc[mt][nt] = zf;

#pragma unroll
      for (int h2 = 0; h2 < 2; ++h2) {
        u32x4 r[16];
        const int kb = khalf * 512 + h2 * 256 + lk8;
        if (l == 0) {
          if (BF16) {
            const u16* srcXb = (const u16*)xv + (size_t)t * NB * NW;
#pragma unroll
            for (int q = 0; q < 8; ++q) {
              r[q] = *(const u32x4*)(srcXb + (size_t)lrow * NW + kb + q * 32);
              r[8 + q] = *(const u32x4*)(srcXb + (size_t)(lrow + 16) * NW + kb + q * 32);
            }
          } else {
            const float* srcXf = (const float*)xv + (size_t)t * NB * NW;
#pragma unroll
            for (int q = 0; q < 8; ++q) {
              const f32x4* p0 = (const f32x4*)(srcXf + (size_t)lrow * NW + kb + q * 32);
              const f32x4* p1 = (const f32x4*)(srcXf + (size_t)(lrow + 16) * NW + kb + q * 32);
              f32x4 x0a = p0[0], x0b = p0[1], x1a = p1[0], x1b = p1[1];
              short8 a0, a1;
#pragma unroll
              for (int j = 0; j < 4; ++j) {
                a0[j] = (short)f2bf(x0a[j]);
                a0[j + 4] = (short)f2bf(x0b[j]);
                a1[j] = (short)f2bf(x1a[j]);
                a1[j + 4] = (short)f2bf(x1b[j]);
              }
              r[q] = as_u4(a0);
              r[8 + q] = as_u4(a1);
            }
          }
        } else {
          const u16* sY = gh + (size_t)((l - 1) * 65 + t + 1) * BW;
          poll_mixed(sY + (size_t)lrow * NW + kb, sY + (size_t)lrow * NW + kb,
                     sY + (size_t)(lrow + 16) * NW + kb, sY + (size_t)(lrow + 16) * NW + kb,
                     zmask, r);
        }
#pragma unroll
        for (int q = 0; q < 8; ++q) {
          const int kt = h2 * 8 + q;
#pragma unroll
          for (int nt = 0; nt < 4; ++nt) {
            acc[0][nt] = __builtin_amdgcn_mfma_f32_16x16x32_bf16(as_s8(r[q]), wfrag[nt][kt], acc[0][nt], 0, 0, 0);
            acc[1][nt] = __builtin_amdgcn_mfma_f32_16x16x32_bf16(as_s8(r[8 + q]), wfrag[nt][kt], acc[1][nt], 0, 0, 0);
          }
        }
      }

      if (khalf == 1) {
#pragma unroll
        for (int mt = 0; mt < 2; ++mt)
#pragma unroll
          for (int nt = 0; nt < 4; ++nt)
#pragma unroll
            for (int e = 0; e < 4; ++e)
              red[gpair][mt][nt][(lane >> 4) * 4 + e][lrow] = acc[mt][nt][e];
      }
      __syncthreads();
      if (khalf == 0) {
#pragma unroll
        for (int mt = 0; mt < 2; ++mt)
#pragma unroll
          for (int nt = 0; nt < 4; ++nt) {
            const int col = (gpair * 2 + (nt >> 1)) * 1024 + ub + (nt & 1) * 16 + lrow;
#pragma unroll
            for (int e = 0; e < 4; ++e) {
              float v = acc[mt][nt][e] + red[gpair][mt][nt][(lane >> 4) * 4 + e][lrow] + bias_r[nt];
              int b = mt * 16 + (lane >> 4) * 4 + e;
              size_t off = ((size_t)(l * 64 + t) * NB + b) * G4 + col;
              if (xg32) {
                float* p = (float*)xg + off;
                asm volatile("global_store_dword %0, %1, off sc0 sc1" : : "v"(p), "v"(v) : "memory");
              } else {
                u16* p = (u16*)xg + off;
                u32 hv = (u32)f2bf(v);
                asm volatile("global_store_short %0, %1, off sc0 sc1" : : "v"(p), "v"(hv) : "memory");
              }
            }
          }
      }
      __syncthreads();  // protect red[] for next step
    }
  }
}

// ---------------------------------------------------------------------------
extern "C" void kernel_launch(void* const* d_in, const int* in_sizes, int n_in,
                              void* d_out, int out_size, void* d_ws, size_t ws_size,
                              hipStream_t stream) {
  const void* x = d_in[0];
  const void* resets = d_in[1];
  const void* c0 = d_in[2];
  const void* h0 = d_in[3];
  const void* Wx = d_in[4];
  const void* Wh = d_in[5];
  const void* bias = d_in[6];

  char* ws = (char*)d_ws;
  u16* gh = (u16*)(ws + GH_OFF);
  u16* lh = (u16*)(ws + LH_OFF);
  void* xg = (void*)(ws + XG_OFF);
  int xg32 = (ws_size >= (size_t)XG_OFF + 134217728ull + 16384ull) ? 1 : 0;
  size_t xgbytes = xg32 ? 134217728ull : 67108864ull;
  char* tail = ws + XG_OFF + xgbytes;
  int* rmask = (int*)tail;
  int* modes = (int*)(tail + 8192);
  u32* tbl = (u32*)(tail + 8192 + 256);
  long n4 = (long)(((size_t)XG_OFF + xgbytes) / 16);

  lstm_setup<<<1, 256, 0, stream>>>(x, resets, modes, rmask, tbl);
  lstm_poison<<<4096, 256, 0, stream>>>((u32*)ws, n4);
  lstm_prep<true><<<512, 256, 0, stream>>>(h0, modes, gh, lh);
  lstm_prep<false><<<512, 256, 0, stream>>>(h0, modes, gh, lh);
  lstm_main<true><<<256, 256, 0, stream>>>(x, Wx, Wh, bias, c0, d_out, modes, rmask, gh, lh, xg, tbl, xg32);
  lstm_main<false><<<256, 256, 0, stream>>>(x, Wx, Wh, bias, c0, d_out, modes, rmask, gh, lh, xg, tbl, xg32);
}

// Round 5
// 1085.870 us; speedup vs baseline: 83.9453x; 83.9453x over previous
//
#include <hip/hip_runtime.h>
#include <stdint.h>

// ============================================================================
// ScannedMultiLayerLSTM: T=64, B=32, W=1024, L=4
// Round 8: producer/consumer wave split (decouple y-path from critical link).
//   - waves 0,1 (Y-engine): ygate[t] = y[t]&Wx partials, run up to 2 steps
//     ahead, double-buffered LDS slots, monotone seq-counter sync.
//   - waves 2,3 (H-engine): poll h[l][t-1] (R3-exact sentinel poll) -> 128
//     MFMAs -> LDS partial -> epilogue (y slot already filled) -> publish.
//   - no __syncthreads in main loop: intra-block sync via LDS atomics
//     (monotone counters yflag/hflag/edone; no resets, no races).
//   - critical link loses: y-side cross-block detect, half the GEMM
//     serialization, 2 full-block barriers.
//   - cross-block publish/poll machinery byte-identical to R3 (verified 3x).
// ============================================================================

typedef unsigned short u16;
typedef unsigned int u32;
typedef __attribute__((ext_vector_type(8))) short short8;
typedef __attribute__((ext_vector_type(4))) float f32x4;
typedef __attribute__((ext_vector_type(4))) unsigned int u32x4;

#define NT 64
#define NB 32
#define NW 1024
#define NLAY 4
#define G4 4096
#define POISON 0xAAAAAAAAu

// workspace layout (bytes)
#define HIST_OFF 0                 // bf16 hist[L][65][B][W] : slot t = h entering step t
#define RMASK_OFF 17104896         // int rmask[T][B] (8192 B)
#define MODE_OFF 17113088          // int modes[2]

__device__ __forceinline__ float bf2f(u16 u) {
  union { u32 i; float f; } v; v.i = ((u32)u) << 16; return v.f;
}
__device__ __forceinline__ u16 f2bf(float f) {
  union { float f; u32 i; } v; v.f = f;
  u32 b = v.i;
  return (u16)((b + 0x7FFFu + ((b >> 16) & 1u)) >> 16);
}
__device__ __forceinline__ float sigmoidf_(float x) { return 1.f / (1.f + __expf(-x)); }
__device__ __forceinline__ float tanhfast(float x) {
  float cx = fminf(fmaxf(x, -15.f), 15.f);
  float e = __expf(2.f * cx);
  return (e - 1.f) / (e + 1.f);
}
union CastU { u32x4 u; short8 s; };
__device__ __forceinline__ short8 as_s8(u32x4 v) { CastU c; c.u = v; return c.s; }
__device__ __forceinline__ u32x4 as_u4(short8 v) { CastU c; c.s = v; return c.u; }

__device__ __forceinline__ bool fresh4(u32x4 v) {
  return (v.x != POISON) && (v.y != POISON) && (v.z != POISON) && (v.w != POISON);
}

// LDS monotone-counter helpers (workgroup scope)
__device__ __forceinline__ void lds_bump(int* p) {
  __threadfence_block();
  if ((threadIdx.x & 63) == 0)
    __hip_atomic_fetch_add(p, 1, __ATOMIC_RELAXED, __HIP_MEMORY_SCOPE_WORKGROUP);
}
__device__ __forceinline__ void lds_wait(int* p, int want) {
  while (__hip_atomic_load(p, __ATOMIC_RELAXED, __HIP_MEMORY_SCOPE_WORKGROUP) < want)
    __builtin_amdgcn_s_sleep(1);
  __threadfence_block();
}

// ---------------------------------------------------------------------------
// R3-exact sentinel poll (verified 3x at ~928us), sleep parameterized.
// All r[] writes are unconditional compile-time-indexed sweeps (no runtime
// indexing, no divergent asm outputs) — the R7 failure mode is excluded.
// ---------------------------------------------------------------------------
template <int SLP>
__device__ __forceinline__ void poll_half(const u16* rowA, const u16* rowB, u32x4 r[16]) {
  for (;;) {
#pragma unroll
    for (int q = 0; q < 8; ++q) {
      asm volatile("global_load_dwordx4 %0, %1, off sc0 sc1" : "=v"(r[q]) : "v"(rowA + q * 32));
      asm volatile("global_load_dwordx4 %0, %1, off sc0 sc1" : "=v"(r[8 + q]) : "v"(rowB + q * 32));
    }
    asm volatile("s_waitcnt vmcnt(0)"
                 : "+v"(r[0]), "+v"(r[1]), "+v"(r[2]), "+v"(r[3]), "+v"(r[4]), "+v"(r[5]),
                   "+v"(r[6]), "+v"(r[7]), "+v"(r[8]), "+v"(r[9]), "+v"(r[10]), "+v"(r[11]),
                   "+v"(r[12]), "+v"(r[13]), "+v"(r[14]), "+v"(r[15])
                 :
                 : "memory");
    bool ok = true;
    const u16* probe = rowA;
    bool have = false;
#pragma unroll
    for (int c = 0; c < 16; ++c) {
      bool f = (r[c].x != POISON) && (r[c].y != POISON) && (r[c].z != POISON) && (r[c].w != POISON);
      if (!f && !have) { probe = (c < 8) ? (rowA + c * 32) : (rowB + (c - 8) * 32); have = true; }
      ok &= f;
    }
    if (ok) return;
    // throttled single-chunk probe until the laggard lands, then full re-sweep
    for (;;) {
      __builtin_amdgcn_s_sleep(SLP);
      u32x4 v;
      asm volatile("global_load_dwordx4 %0, %1, off sc0 sc1" : "=v"(v) : "v"(probe));
      asm volatile("s_waitcnt vmcnt(0)" : "+v"(v) : : "memory");
      if ((v.x != POISON) && (v.y != POISON) && (v.z != POISON) && (v.w != POISON)) break;
    }
  }
}

// ---------------------------------------------------------------------------
// setup: detect dtypes, normalize resets. 1 block x 256 threads.
// ---------------------------------------------------------------------------
__global__ void lstm_setup(const void* __restrict__ x, const void* __restrict__ resets,
                           int* __restrict__ modes, int* __restrict__ rmask) {
  __shared__ int votes_bf16, bad_int, bad_float;
  __shared__ int sm_rmode;
  int tid = threadIdx.x;
  if (tid == 0) { votes_bf16 = 0; bad_int = 0; bad_float = 0; }
  __syncthreads();
  {
    u32 w = ((const u32*)x)[tid];
    int e = (int)((w >> 7) & 0xFFu);
    if (e >= 100 && e <= 140) atomicAdd(&votes_bf16, 1);
  }
  if (tid < 128) {
    u32 r = ((const u32*)resets)[tid];
    if (r > 1u) atomicAdd(&bad_int, 1);
    if (r != 0u && r != 0x3F800000u) atomicAdd(&bad_float, 1);
  }
  __syncthreads();
  if (tid == 0) {
    int mbf = (votes_bf16 >= 192) ? 1 : 0;
    int rmode;
    if (bad_int == 0) rmode = 1;
    else if (bad_float == 0) rmode = 2;
    else rmode = 0;
    modes[0] = mbf;
    modes[1] = rmode;
    sm_rmode = rmode;
  }
  __syncthreads();
  int rmode = sm_rmode;
#pragma unroll
  for (int k = 0; k < 8; ++k) {
    int idx = tid * 8 + k;
    int val;
    if (rmode == 1) val = (((const int*)resets)[idx] != 0);
    else if (rmode == 2) val = (((const u32*)resets)[idx] != 0u);
    else val = (((const unsigned char*)resets)[idx] != 0);
    rmask[idx] = val;
  }
}

// ---------------------------------------------------------------------------
// poison hist slots 1..64 of every layer to the sentinel. 4096 blocks x 256.
// ---------------------------------------------------------------------------
__global__ void lstm_poison(u32* __restrict__ hist32) {
  int g = (blockIdx.x * 256 + threadIdx.x) * 4; // u32 index, 4,194,304 total
  int l = g >> 20;                              // 1,048,576 u32 per layer
  int r = g & 1048575;
  u32x4 v = {POISON, POISON, POISON, POISON};
  *(u32x4*)(hist32 + ((size_t)l * 65 + 1) * 16384 + r) = v;
}

// ---------------------------------------------------------------------------
// prep: copy h0 -> hist slot0 (bf16). 512 blocks x 256.
// ---------------------------------------------------------------------------
template <bool BF16>
__global__ void lstm_prep(const void* __restrict__ h0, const int* __restrict__ modes,
                          u16* __restrict__ hist) {
  if ((modes[0] != 0) != BF16) return;
  int idx = blockIdx.x * 256 + threadIdx.x; // 0..131071 over [L][B][W]
  int l = idx >> 15;
  int rem = idx & 32767;
  float hv;
  if (BF16) hv = bf2f(((const u16*)h0)[idx]);
  else      hv = ((const float*)h0)[idx];
  hist[(size_t)l * (65 * NB * NW) + rem] = f2bf(hv);
}

// ---------------------------------------------------------------------------
// main persistent kernel. 256 blocks x 256 threads (4 waves).
// waves 0,1: Y-engine (y@Wx, 2-deep run-ahead). waves 2,3: H-engine
// (h@Wh + epilogue + publish) — the critical path.
// ---------------------------------------------------------------------------
template <bool BF16>
__global__ __launch_bounds__(256, 1) void lstm_main(
    const void* __restrict__ xv, const void* __restrict__ Wxv,
    const void* __restrict__ Whv, const void* __restrict__ biasv,
    const void* __restrict__ c0v,
    void* __restrict__ outv, const int* __restrict__ modes,
    const int* __restrict__ rmask, u16* __restrict__ hist) {
  if ((modes[0] != 0) != BF16) return;

  const int l = blockIdx.x >> 6;      // layer
  const int s = blockIdx.x & 63;      // hidden-slice
  const int hb = s * 16;
  const int tid = threadIdx.x;
  const int wave = tid >> 6;
  const int lane = tid & 63;
  const bool ypart = (wave < 2);      // waves 0,1: y@Wx; waves 2,3: h@Wh
  const int krel = (wave & 1) * 512;  // K offset within this engine's 1024 rows
  const int lrow = lane & 15;
  const int lk8 = (lane >> 4) * 8;

  // partial-sum buffers, double-buffered by step parity
  __shared__ float yred[2][2][2][4][16][17]; // [slot][ywave][mt][gate][row][col+pad]
  __shared__ float hred[2][2][2][4][16][17]; // [slot][hwave][mt][gate][row][col+pad]
  __shared__ int yflag, hflag, edone;        // monotone counters (+1 per wave per step)

  if (tid == 0) { yflag = 0; hflag = 0; edone = 0; }

  // ---- one-time weight preload: B-fragments B[k][n], n=lane&15, k=lk8+j ----
  short8 wfrag[4][16]; // [gate][ktile]
  {
    const size_t base = (size_t)l * NW * G4;
#pragma unroll
    for (int g = 0; g < 4; ++g) {
#pragma unroll
      for (int kt = 0; kt < 16; ++kt) {
        size_t off = base + (size_t)(krel + kt * 32 + lk8) * G4 + (size_t)(g * 1024 + hb + lrow);
        short8 v;
        if (BF16) {
          const u16* p = (ypart ? (const u16*)Wxv : (const u16*)Whv) + off;
#pragma unroll
          for (int j = 0; j < 8; ++j) v[j] = (short)p[(size_t)j * G4];
        } else {
          const float* p = (ypart ? (const float*)Wxv : (const float*)Whv) + off;
#pragma unroll
          for (int j = 0; j < 8; ++j) v[j] = (short)f2bf(p[(size_t)j * G4]);
        }
        wfrag[g][kt] = v;
      }
    }
  }
  __syncthreads();  // weights + flags ready; last barrier in the kernel

  if (ypart) {
    // ======================= Y-ENGINE (waves 0,1) =======================
#pragma unroll 1
    for (int t = 0; t < NT; ++t) {
      const int slot = t & 1;
      const u16* srcY = hist + ((size_t)(l - 1) * 65 + (t + 1)) * (NB * NW);
      const u16* srcXb = (const u16*)xv + (size_t)t * NB * NW;
      const float* srcXf = (const float*)xv + (size_t)t * NB * NW;

      f32x4 acc[2][4];
      f32x4 zf = {0.f, 0.f, 0.f, 0.f};
#pragma unroll
      for (int mt = 0; mt < 2; ++mt)
#pragma unroll
        for (int g = 0; g < 4; ++g) acc[mt][g] = zf;

#pragma unroll
      for (int half = 0; half < 2; ++half) {
        u32x4 r[16];
        const int kbase = krel + half * 256 + lk8;
        if (l > 0) {
          poll_half<16>(srcY + (size_t)lrow * NW + kbase, srcY + (size_t)(lrow + 16) * NW + kbase, r);
        } else if (BF16) {
#pragma unroll
          for (int q = 0; q < 8; ++q) {
            r[q] = *(const u32x4*)(srcXb + (size_t)lrow * NW + kbase + q * 32);
            r[8 + q] = *(const u32x4*)(srcXb + (size_t)(lrow + 16) * NW + kbase + q * 32);
          }
        } else {
#pragma unroll
          for (int q = 0; q < 8; ++q) {
            const f32x4* p0 = (const f32x4*)(srcXf + (size_t)lrow * NW + kbase + q * 32);
            const f32x4* p1 = (const f32x4*)(srcXf + (size_t)(lrow + 16) * NW + kbase + q * 32);
            f32x4 x0a = p0[0], x0b = p0[1], x1a = p1[0], x1b = p1[1];
            short8 a0, a1;
#pragma unroll
            for (int j = 0; j < 4; ++j) {
              a0[j] = (short)f2bf(x0a[j]);
              a0[j + 4] = (short)f2bf(x0b[j]);
              a1[j] = (short)f2bf(x1a[j]);
              a1[j + 4] = (short)f2bf(x1b[j]);
            }
            r[q] = as_u4(a0);
            r[8 + q] = as_u4(a1);
          }
        }
#pragma unroll
        for (int q = 0; q < 8; ++q) {
          const int kt = half * 8 + q;
#pragma unroll
          for (int g = 0; g < 4; ++g) {
            acc[0][g] = __builtin_amdgcn_mfma_f32_16x16x32_bf16(as_s8(r[q]), wfrag[g][kt], acc[0][g], 0, 0, 0);
            acc[1][g] = __builtin_amdgcn_mfma_f32_16x16x32_bf16(as_s8(r[8 + q]), wfrag[g][kt], acc[1][g], 0, 0, 0);
          }
        }
      }

      // slot free when both H-epilogues of step t-2 are done
      if (t >= 2) lds_wait(&edone, 2 * (t - 1));
#pragma unroll
      for (int mt = 0; mt < 2; ++mt)
#pragma unroll
        for (int g = 0; g < 4; ++g)
#pragma unroll
          for (int e = 0; e < 4; ++e)
            yred[slot][wave][mt][g][(lane >> 4) * 4 + e][lrow] = acc[mt][g][e];
      lds_bump(&yflag);
    }
  } else {
    // ======================= H-ENGINE (waves 2,3) =======================
    const int hw = wave - 2;
    const int tid2 = tid - 128;       // 0..127
    const int eb = tid2 >> 2;         // batch row 0..31
    const int eu = (tid2 & 3) * 4;    // unit base within slice (0,4,8,12)
    const int emt = eb >> 4, er = eb & 15;

    float bias_r[4][4];
#pragma unroll
    for (int g = 0; g < 4; ++g)
#pragma unroll
      for (int j = 0; j < 4; ++j) {
        int bidx = l * G4 + g * 1024 + hb + eu + j;
        bias_r[g][j] = BF16 ? bf2f(((const u16*)biasv)[bidx]) : ((const float*)biasv)[bidx];
      }

    float creg[4] = {0.f, 0.f, 0.f, 0.f};

#pragma unroll 1
    for (int t = 0; t < NT; ++t) {
      const int slot = t & 1;
      const u16* srcH = hist + ((size_t)l * 65 + t) * (NB * NW);  // h[l][t-1]
      int rm0 = rmask[t * NB + lrow];
      int rm1 = rmask[t * NB + 16 + lrow];

      f32x4 acc[2][4];
      f32x4 zf = {0.f, 0.f, 0.f, 0.f};
#pragma unroll
      for (int mt = 0; mt < 2; ++mt)
#pragma unroll
        for (int g = 0; g < 4; ++g) acc[mt][g] = zf;

#pragma unroll
      for (int half = 0; half < 2; ++half) {
        u32x4 r[16];
        const int kbase = krel + half * 256 + lk8;
        poll_half<4>(srcH + (size_t)lrow * NW + kbase, srcH + (size_t)(lrow + 16) * NW + kbase, r);
        u32x4 z4 = {0u, 0u, 0u, 0u};
        if (rm0) {
#pragma unroll
          for (int q = 0; q < 8; ++q) r[q] = z4;
        }
        if (rm1) {
#pragma unroll
          for (int q = 0; q < 8; ++q) r[8 + q] = z4;
        }
#pragma unroll
        for (int q = 0; q < 8; ++q) {
          const int kt = half * 8 + q;
#pragma unroll
          for (int g = 0; g < 4; ++g) {
            acc[0][g] = __builtin_amdgcn_mfma_f32_16x16x32_bf16(as_s8(r[q]), wfrag[g][kt], acc[0][g], 0, 0, 0);
            acc[1][g] = __builtin_amdgcn_mfma_f32_16x16x32_bf16(as_s8(r[8 + q]), wfrag[g][kt], acc[1][g], 0, 0, 0);
          }
        }
      }

      // hred slot free when both epilogues of step t-2 are done
      if (t >= 2) lds_wait(&edone, 2 * (t - 1));
#pragma unroll
      for (int mt = 0; mt < 2; ++mt)
#pragma unroll
        for (int g = 0; g < 4; ++g)
#pragma unroll
          for (int e = 0; e < 4; ++e)
            hred[slot][hw][mt][g][(lane >> 4) * 4 + e][lrow] = acc[mt][g][e];
      lds_bump(&hflag);

      // wait: both h-partials, both y-partials of this step
      lds_wait(&hflag, 2 * (t + 1));
      lds_wait(&yflag, 2 * (t + 1));

      // ---- epilogue: 4 cells per thread (eb, eu..eu+3) ----
      {
        int rm = rmask[t * NB + eb];
        float hn[4];
#pragma unroll
        for (int j = 0; j < 4; ++j) {
          int n = eu + j;
          float gv[4];
#pragma unroll
          for (int g = 0; g < 4; ++g)
            gv[g] = yred[slot][0][emt][g][er][n] + yred[slot][1][emt][g][er][n] +
                    hred[slot][0][emt][g][er][n] + hred[slot][1][emt][g][er][n] + bias_r[g][j];
          float c_old = creg[j];
          if (t == 0) {
            int cidx = (l * NB + eb) * NW + hb + n;
            c_old = BF16 ? bf2f(((const u16*)c0v)[cidx]) : ((const float*)c0v)[cidx];
          }
          if (rm) c_old = 0.f;
          float ci = sigmoidf_(gv[0]);
          float cf = sigmoidf_(gv[1]);
          float cg = tanhfast(gv[2]);
          float co = sigmoidf_(gv[3]);
          float cn = cf * c_old + ci * cg;
          hn[j] = co * tanhfast(cn);
          creg[j] = cn;
        }
        // publish h (write-through, packed 2x bf16) — consumers sentinel-poll this
        u32 hp0 = (u32)f2bf(hn[0]) | ((u32)f2bf(hn[1]) << 16);
        u32 hp1 = (u32)f2bf(hn[2]) | ((u32)f2bf(hn[3]) << 16);
        size_t hoff = ((size_t)l * 65 + (t + 1)) * (NB * NW) + (size_t)eb * NW + hb + eu;
        u32* hptr = (u32*)(hist + hoff);
        __hip_atomic_store(hptr, hp0, __ATOMIC_RELAXED, __HIP_MEMORY_SCOPE_AGENT);
        __hip_atomic_store(hptr + 1, hp1, __ATOMIC_RELAXED, __HIP_MEMORY_SCOPE_AGENT);
        // y output (layer 3)
        if (l == NLAY - 1) {
          size_t oy = ((size_t)t * NB + eb) * NW + hb + eu;
          if (BF16) {
            ((u32*)outv)[oy >> 1] = hp0;
            ((u32*)outv)[(oy >> 1) + 1] = hp1;
          } else {
            float* op = (float*)outv + oy;
            op[0] = hn[0]; op[1] = hn[1]; op[2] = hn[2]; op[3] = hn[3];
          }
        }
        // final c/h outputs
        if (t == NT - 1) {
          size_t oc = (size_t)NT * NB * NW + ((size_t)l * NB + eb) * NW + hb + eu;
          size_t oh = oc + (size_t)NLAY * NB * NW;
          if (BF16) {
            u32 cp0 = (u32)f2bf(creg[0]) | ((u32)f2bf(creg[1]) << 16);
            u32 cp1 = (u32)f2bf(creg[2]) | ((u32)f2bf(creg[3]) << 16);
            ((u32*)outv)[oc >> 1] = cp0;
            ((u32*)outv)[(oc >> 1) + 1] = cp1;
            ((u32*)outv)[oh >> 1] = hp0;
            ((u32*)outv)[(oh >> 1) + 1] = hp1;
          } else {
            float* ov = (float*)outv;
            ov[oc + 0] = creg[0]; ov[oc + 1] = creg[1]; ov[oc + 2] = creg[2]; ov[oc + 3] = creg[3];
            ov[oh + 0] = hn[0]; ov[oh + 1] = hn[1]; ov[oh + 2] = hn[2]; ov[oh + 3] = hn[3];
          }
        }
      }
      lds_bump(&edone);
    }
  }
}

// ---------------------------------------------------------------------------
extern "C" void kernel_launch(void* const* d_in, const int* in_sizes, int n_in,
                              void* d_out, int out_size, void* d_ws, size_t ws_size,
                              hipStream_t stream) {
  const void* x = d_in[0];
  const void* resets = d_in[1];
  const void* c0 = d_in[2];
  const void* h0 = d_in[3];
  const void* Wx = d_in[4];
  const void* Wh = d_in[5];
  const void* bias = d_in[6];

  char* ws = (char*)d_ws;
  u16* hist = (u16*)(ws + HIST_OFF);
  int* rmask = (int*)(ws + RMASK_OFF);
  int* modes = (int*)(ws + MODE_OFF);

  lstm_setup<<<1, 256, 0, stream>>>(x, resets, modes, rmask);
  lstm_poison<<<4096, 256, 0, stream>>>((u32*)hist);
  lstm_prep<true><<<512, 256, 0, stream>>>(h0, modes, hist);
  lstm_prep<false><<<512, 256, 0, stream>>>(h0, modes, hist);
  lstm_main<true><<<256, 256, 0, stream>>>(x, Wx, Wh, bias, c0, d_out, modes, rmask, hist);
  lstm_main<false><<<256, 256, 0, stream>>>(x, Wx, Wh, bias, c0, d_out, modes, rmask, hist);
}